// Round 1
// baseline (563.806 us; speedup 1.0000x reference)
//
#include <hip/hip_runtime.h>
#include <hip/hip_bf16.h>
#include <math.h>

// Problem constants (match reference)
#define IN_C 31
#define OUT_C 31
#define GRIDSZ 5
#define KORD 3
#define NUM_BASIS 8            // GRIDSZ + KORD
#define COEF_LEN 7688          // IN_C*OUT_C*NUM_BASIS
#define UW_OFF 7688
#define RW_OFF 8649            // 7688 + 961
#define NPIX 16384             // 128*128

// Layout: 8 threads per pixel (ot = 0..7), each handles o in {ot, ot+8, ot+16, ot+24} (<31).
// Block: 256 threads = 32 pixels. Grid: 512 blocks = 16384 pixels.
// Everything in registers; weights stream from L2 (1.2 MB, fully cached).

__global__ __launch_bounds__(256) void kan_fused_kernel(
    const float* __restrict__ x,     // (31, 16384)
    const float* __restrict__ gw,    // (9610, 31)
    const float* __restrict__ gb,    // (9610,)
    float* __restrict__ out)         // (31, 16384)
{
    const int t  = threadIdx.x;
    const int p  = t & 31;           // local pixel
    const int ot = t >> 5;           // 0..7 output-channel split
    const int pix = blockIdx.x * 32 + p;

    // Load the pixel's 31 channels into registers (coalesced across lanes).
    float xl[IN_C];
#pragma unroll
    for (int c = 0; c < IN_C; ++c)
        xl[c] = x[c * NPIX + pix];

    float y[4] = {0.f, 0.f, 0.f, 0.f};

    // Extended knots: g[j] = (j-3)*h - 1, h = 2/5. All compile-time constants
    // after unrolling (matches reference arithmetic: float(j-3)*float(0.4)-1).
    const float h = 2.0f / (float)GRIDSZ;

    for (int i = 0; i < IN_C; ++i) {
        const float xv = xl[i];

        // ---- Cox-de Boor basis (exact replication of reference recursion) ----
        float g[GRIDSZ + 2 * KORD + 1];  // 12 knots
#pragma unroll
        for (int j = 0; j < GRIDSZ + 2 * KORD + 1; ++j)
            g[j] = (float)(j - KORD) * h - 1.0f;

        float b[GRIDSZ + 2 * KORD];      // 11 -> 10 -> 9 -> 8
#pragma unroll
        for (int j = 0; j < GRIDSZ + 2 * KORD; ++j)
            b[j] = (xv >= g[j] && xv < g[j + 1]) ? 1.0f : 0.0f;

#pragma unroll
        for (int pd = 1; pd <= KORD; ++pd) {
#pragma unroll
            for (int j = 0; j < GRIDSZ + 2 * KORD - pd; ++j) {
                // Denominators are compile-time constants -> folds to multiplies.
                const float left  = (xv - g[j]) * (1.0f / (g[j + pd] - g[j])) * b[j];
                const float right = (g[j + pd + 1] - xv) * (1.0f / (g[j + pd + 1] - g[j + 1])) * b[j + 1];
                b[j] = left + right;
            }
        }

        // silu(x) = x / (1 + exp(-x))
        const float sil = xv / (1.0f + expf(-xv));

#pragma unroll
        for (int j = 0; j < 4; ++j) {
            const int o = ot + 8 * j;
            if (o < OUT_C) {
                const int po = i * OUT_C + o;

                // spline_{io} = sum_k basis_k * (gw_coef[po,k,:] . x + gb_coef[po,k])
                const float* wc = gw + (size_t)po * NUM_BASIS * IN_C;
                float spline = 0.f;
#pragma unroll
                for (int k = 0; k < NUM_BASIS; ++k) {
                    float ck = gb[po * NUM_BASIS + k];
#pragma unroll
                    for (int c = 0; c < IN_C; ++c)
                        ck = fmaf(wc[k * IN_C + c], xl[c], ck);
                    spline = fmaf(b[k], ck, spline);
                }

                // uw_{io}, rw_{io}
                const float* wu = gw + (size_t)(UW_OFF + po) * IN_C;
                const float* wr = gw + (size_t)(RW_OFF + po) * IN_C;
                float uwv = gb[UW_OFF + po];
                float rwv = gb[RW_OFF + po];
#pragma unroll
                for (int c = 0; c < IN_C; ++c) {
                    uwv = fmaf(wu[c], xl[c], uwv);
                    rwv = fmaf(wr[c], xl[c], rwv);
                }

                y[j] += uwv * spline + sil * rwv;
            }
        }
    }

#pragma unroll
    for (int j = 0; j < 4; ++j) {
        const int o = ot + 8 * j;
        if (o < OUT_C)
            out[o * NPIX + pix] = y[j];
    }
}

extern "C" void kernel_launch(void* const* d_in, const int* in_sizes, int n_in,
                              void* d_out, int out_size, void* d_ws, size_t ws_size,
                              hipStream_t stream) {
    const float* x  = (const float*)d_in[0];
    const float* gw = (const float*)d_in[1];
    const float* gb = (const float*)d_in[2];
    float* out = (float*)d_out;

    dim3 grid(NPIX / 32);   // 512 blocks
    dim3 block(256);        // 32 pixels x 8 o-split threads
    hipLaunchKernelGGL(kan_fused_kernel, grid, block, 0, stream, x, gw, gb, out);
}

// Round 2
// 271.520 us; speedup vs baseline: 2.0765x; 2.0765x over previous
//
#include <hip/hip_runtime.h>
#include <hip/hip_bf16.h>
#include <math.h>

// Problem constants (match reference)
#define IN_C 31
#define OUT_C 31
#define GRIDSZ 5
#define KORD 3
#define NUM_BASIS 8            // GRIDSZ + KORD
#define UW_OFF 7688            // COEF_LEN
#define RW_OFF 8649            // COEF_LEN + UW_LEN
#define NPIX 16384             // 128*128

// Layout: one pixel per LANE (64 pixels per wave). Block = 1024 threads =
// 16 waves, all covering the same 64 pixels; wave w owns output channels
// {2w, 2w+1} (wave 15 owns only o=30). Grid = 256 blocks (= 256 CUs),
// 4096 waves total = 4 waves/SIMD.
//
// Weight addresses depend only on (loop indices, readfirstlane(waveid)) ->
// wave-uniform -> compiler emits scalar s_load; each 64B scalar fetch feeds
// 16 wave-wide v_fmac_f32 (weight in SGPR, x in VGPR). This removes the
// 1-vector-load-per-fma issue bottleneck of the previous version.

__global__ __launch_bounds__(1024) void kan_fused2_kernel(
    const float* __restrict__ x,     // (31, 16384)
    const float* __restrict__ gw,    // (9610, 31)
    const float* __restrict__ gb,    // (9610,)
    float* __restrict__ out)         // (31, 16384)
{
    const int lane = threadIdx.x & 63;
    const int w    = __builtin_amdgcn_readfirstlane(threadIdx.x >> 6); // 0..15, SGPR
    const int pix  = blockIdx.x * 64 + lane;
    const int o0   = w * 2;
    const int nO   = (o0 + 2 <= OUT_C) ? 2 : (OUT_C - o0);   // wave 15 -> 1

    // Pixel's 31 channels in registers (coalesced: lane = consecutive pixel).
    float xl[IN_C];
#pragma unroll
    for (int c = 0; c < IN_C; ++c)
        xl[c] = x[c * NPIX + pix];

    float y0 = 0.f, y1 = 0.f;

    const float h = 2.0f / (float)GRIDSZ;

#pragma unroll 1
    for (int i = 0; i < IN_C; ++i) {
        const float xv = xl[i];

        // ---- Cox-de Boor basis (exact replication of reference recursion) ----
        float g[GRIDSZ + 2 * KORD + 1];  // 12 knots, compile-time constants
#pragma unroll
        for (int j = 0; j < GRIDSZ + 2 * KORD + 1; ++j)
            g[j] = (float)(j - KORD) * h - 1.0f;

        float b[GRIDSZ + 2 * KORD];      // 11 -> 10 -> 9 -> 8
#pragma unroll
        for (int j = 0; j < GRIDSZ + 2 * KORD; ++j)
            b[j] = (xv >= g[j] && xv < g[j + 1]) ? 1.0f : 0.0f;

#pragma unroll
        for (int pd = 1; pd <= KORD; ++pd) {
#pragma unroll
            for (int j = 0; j < GRIDSZ + 2 * KORD - pd; ++j) {
                const float left  = (xv - g[j]) * (1.0f / (g[j + pd] - g[j])) * b[j];
                const float right = (g[j + pd + 1] - xv) * (1.0f / (g[j + pd + 1] - g[j + 1])) * b[j + 1];
                b[j] = left + right;
            }
        }

        const float sil = xv / (1.0f + expf(-xv));

#pragma unroll
        for (int jo = 0; jo < 2; ++jo) {
            if (jo < nO) {                       // wave-uniform guard
                const int o  = o0 + jo;
                const int po = i * OUT_C + o;

                // ---- spline = sum_k basis_k * (gw_coef[po,k,:] . x + gb) ----
                const float* wc = gw + (size_t)po * (NUM_BASIS * IN_C);
                const float* cb = gb + po * NUM_BASIS;
                float sp0 = 0.f, sp1 = 0.f;
#pragma unroll
                for (int k = 0; k < NUM_BASIS; ++k) {
                    // two independent accumulator chains for ILP
                    float cka = cb[k];
                    float ckb = 0.f;
#pragma unroll
                    for (int c = 0; c + 1 < IN_C; c += 2) {
                        cka = fmaf(wc[k * IN_C + c],     xl[c],     cka);
                        ckb = fmaf(wc[k * IN_C + c + 1], xl[c + 1], ckb);
                    }
                    cka = fmaf(wc[k * IN_C + (IN_C - 1)], xl[IN_C - 1], cka);
                    const float ck = cka + ckb;
                    if (k & 1) sp1 = fmaf(b[k], ck, sp1);
                    else       sp0 = fmaf(b[k], ck, sp0);
                }
                const float spline = sp0 + sp1;

                // ---- uw, rw dots ----
                const float* wu = gw + (size_t)(UW_OFF + po) * IN_C;
                const float* wr = gw + (size_t)(RW_OFF + po) * IN_C;
                float uwv = gb[UW_OFF + po];
                float rwv = gb[RW_OFF + po];
#pragma unroll
                for (int c = 0; c < IN_C; ++c) {
                    uwv = fmaf(wu[c], xl[c], uwv);
                    rwv = fmaf(wr[c], xl[c], rwv);
                }

                const float yv = uwv * spline + sil * rwv;
                if (jo == 0) y0 += yv; else y1 += yv;
            }
        }
    }

    out[o0 * NPIX + pix] = y0;
    if (nO > 1)
        out[(o0 + 1) * NPIX + pix] = y1;
}

extern "C" void kernel_launch(void* const* d_in, const int* in_sizes, int n_in,
                              void* d_out, int out_size, void* d_ws, size_t ws_size,
                              hipStream_t stream) {
    const float* x  = (const float*)d_in[0];
    const float* gw = (const float*)d_in[1];
    const float* gb = (const float*)d_in[2];
    float* out = (float*)d_out;

    dim3 grid(NPIX / 64);    // 256 blocks
    dim3 block(1024);        // 16 waves x 64 lanes; block owns 64 pixels
    hipLaunchKernelGGL(kan_fused2_kernel, grid, block, 0, stream, x, gw, gb, out);
}